// Round 12
// baseline (112.521 us; speedup 1.0000x reference)
//
#include <hip/hip_runtime.h>
#include <hip/hip_fp16.h>

typedef _Float16 f16x8 __attribute__((ext_vector_type(8)));
typedef _Float16 f16x4 __attribute__((ext_vector_type(4)));
typedef float f32x4 __attribute__((ext_vector_type(4)));
typedef float f32x16 __attribute__((ext_vector_type(16)));

#define MFMA16(a, b, c) __builtin_amdgcn_mfma_f32_16x16x32_f16(a, b, c, 0, 0, 0)
#define MFMA32(a, b, c) __builtin_amdgcn_mfma_f32_32x32x16_f16(a, b, c, 0, 0, 0)

__device__ __forceinline__ void gload_lds16(const _Float16* g, void* l) {
    __builtin_amdgcn_global_load_lds(
        (const __attribute__((address_space(1))) void*)g,
        (__attribute__((address_space(3))) void*)l, 16, 0, 0);
}

__device__ __forceinline__ unsigned pkh(float a, float b) {
    typedef __fp16 fp16v2 __attribute__((ext_vector_type(2)));
    fp16v2 h = __builtin_amdgcn_cvt_pkrtz(a, b);
    return __builtin_bit_cast(unsigned, h);
}

__device__ __forceinline__ float fexp2(float x) {
#if __has_builtin(__builtin_amdgcn_exp2f)
    return __builtin_amdgcn_exp2f(x);
#else
    return exp2f(x);
#endif
}

// -------------------------------------------- transpose x -> f16 [b][n][c] + BN stats
__global__ __launch_bounds__(256) void trans_stats_kernel(
    const float* __restrict__ x, _Float16* __restrict__ xt,
    float* __restrict__ sums)
{
    __shared__ float tile[64][65];
    int t = threadIdx.x;
    int b = blockIdx.z, c0 = blockIdx.y * 64, n0 = blockIdx.x * 64;
    int nl = t & 63, cq = t >> 6;
#pragma unroll
    for (int r = 0; r < 16; ++r) {
        int cl = cq * 16 + r;
        tile[cl][nl] = x[((size_t)b * 256 + c0 + cl) * 2048 + n0 + nl];
    }
    __syncthreads();
    int cl2 = t & 63, nq = t >> 6;
#pragma unroll
    for (int r = 0; r < 16; ++r) {
        int nl2 = nq * 16 + r;
        xt[((size_t)b * 2048 + n0 + nl2) * 256 + c0 + cl2] = (_Float16)tile[cl2][nl2];
    }
    if (t < 64) {
        float s = 0.f, ss = 0.f;
#pragma unroll
        for (int j = 0; j < 64; ++j) {
            float v = tile[t][j];
            s += v; ss += v * v;
        }
        atomicAdd(&sums[c0 + t], s);
        atomicAdd(&sums[256 + c0 + t], ss);
    }
}

// ---------------------------------------------------------------- fold BN into weights
__global__ __launch_bounds__(256) void fold_kernel(
    const float* __restrict__ Wq, const float* __restrict__ Wk,
    const float* __restrict__ Wv, const float* __restrict__ Wp,
    const float* __restrict__ bq, const float* __restrict__ bk,
    const float* __restrict__ bv,
    const float* __restrict__ gamma, const float* __restrict__ beta,
    const float* __restrict__ sums,
    _Float16* __restrict__ wbf, float* __restrict__ bfold)
{
    int t = threadIdx.x, bid = blockIdx.x;
    if (bid >= 192) {                       // cast Wp
        int i = (bid - 192) * 256 + t;
        wbf[3 * 65536 + i] = (_Float16)Wp[i];
        return;
    }
    __shared__ float sc[256], sh[256];
    if (t < 256) {
        float mean = sums[t] * (1.f / 16384.f);
        float var  = sums[256 + t] * (1.f / 16384.f) - mean * mean;
        float rstd = rsqrtf(var + 1e-5f);
        float s = rstd * gamma[t];
        sc[t] = s;
        sh[t] = beta[t] - mean * s;
    }
    __syncthreads();
    const float QS = 0.09016844005556021f;  // log2(e)/16
    int mat = bid >> 6;                     // 0=q 1=k 2=v
    int o = (bid & 63) * 4 + (t >> 6);
    int lane = t & 63;
    const float* W  = (mat == 0) ? Wq : (mat == 1) ? Wk : Wv;
    const float* bb = (mat == 0) ? bq : (mat == 1) ? bk : bv;
    float qs = (mat == 0) ? QS : 1.f;
    float dot = 0.f;
    _Float16* wd = wbf + mat * 65536 + o * 256;
#pragma unroll
    for (int i = 0; i < 4; ++i) {
        int c = lane * 4 + i;
        float wv_ = W[o * 256 + c];
        dot += wv_ * sh[c];
        wd[c] = (_Float16)(wv_ * sc[c] * qs);
    }
#pragma unroll
    for (int off = 32; off > 0; off >>= 1) dot += __shfl_down(dot, off, 64);
    if (lane == 0) bfold[mat * 256 + o] = qs * (bb[o] + dot);
}

// ---------------------------------------------------------------- NT GEMM (m97-style)
// EPI: 0 = row-major C; 1 = K-fragment layout (row = k-channel, col = m);
//      2 = V-fragment layout (row = m, col = d).
template<int BN, int WGM, int WGN, typename OT, bool BIAS_I, bool RES, int EPI>
__global__ __launch_bounds__(256, 3) void gemm_nt(
    const _Float16* __restrict__ Aall, long strideA,
    const _Float16* __restrict__ Ball, long strideB,
    const float* __restrict__ bias,
    const float* __restrict__ resid, long strideR,
    OT* __restrict__ Call, long strideC, int Nn)
{
    constexpr int BM = 128;
    constexpr int WR = BM / WGM;
    constexpr int WC = BN / WGN;
    constexpr int FM = WR / 16, FN = WC / 16;
    constexpr int BUFSZ = 8192 + BN * 64;
    constexpr int NI = 8 + BN / 16;
    constexpr int PW = NI / 4;

    int b = blockIdx.z;
    const _Float16* A  = Aall + (size_t)b * strideA;
    const _Float16* Bm = Ball + (size_t)b * strideB;
    OT* C = Call + (size_t)b * strideC;
    int i0 = blockIdx.y * BM, j0 = blockIdx.x * BN;

    __shared__ __align__(16) char lds[2 * BUFSZ];

    int t = threadIdx.x, lane = t & 63, w = t >> 6;
    int lr = lane & 15, lg = lane >> 4;
    int wm = w % WGM, wn = w / WGM;

    int soff = (lane >> 2) * 256 + (((lane & 3) ^ ((lane >> 3) & 3))) * 8;
    int lgx16 = ((lg ^ ((lr >> 1) & 3))) * 16;

    f32x4 acc[FM][FN] = {};

    auto stage = [&](int kk, int buf) {
#pragma unroll
        for (int i = 0; i < PW; ++i) {
            int u = w * PW + i;
            if (u < 8)
                gload_lds16(A + (size_t)(i0 + u * 16) * 256 + kk * 32 + soff,
                            lds + buf * BUFSZ + u * 1024);
            else
                gload_lds16(Bm + (size_t)(j0 + (u - 8) * 16) * 256 + kk * 32 + soff,
                            lds + buf * BUFSZ + 8192 + (u - 8) * 1024);
        }
    };

    stage(0, 0);
    __syncthreads();
    int buf = 0;
#pragma unroll
    for (int kk = 0; kk < 8; ++kk) {
        if (kk + 1 < 8) stage(kk + 1, buf ^ 1);
        const char* ab = lds + buf * BUFSZ;
        const char* bb = ab + 8192;
        f16x8 af[FM], bf[FN];
#pragma unroll
        for (int f = 0; f < FM; ++f)
            af[f] = *(const f16x8*)(ab + (wm * WR + f * 16 + lr) * 64 + lgx16);
#pragma unroll
        for (int f = 0; f < FN; ++f)
            bf[f] = *(const f16x8*)(bb + (wn * WC + f * 16 + lr) * 64 + lgx16);
        __builtin_amdgcn_s_setprio(1);
#pragma unroll
        for (int fm = 0; fm < FM; ++fm)
#pragma unroll
            for (int fn = 0; fn < FN; ++fn)
                acc[fm][fn] = MFMA16(af[fm], bf[fn], acc[fm][fn]);
        __builtin_amdgcn_s_setprio(0);
        __syncthreads();
        buf ^= 1;
    }
    if constexpr (EPI == 0) {
#pragma unroll
        for (int fm = 0; fm < FM; ++fm)
#pragma unroll
            for (int fn = 0; fn < FN; ++fn)
#pragma unroll
                for (int rr = 0; rr < 4; ++rr) {
                    int row = i0 + wm * WR + fm * 16 + lg * 4 + rr;
                    int col = j0 + wn * WC + fn * 16 + lr;
                    float vv = acc[fm][fn][rr] + (BIAS_I ? bias[row] : bias[col]);
                    if (RES) vv += resid[(size_t)b * strideR + (size_t)row * Nn + col];
                    C[(size_t)row * Nn + col] = (OT)vv;
                }
    } else {
#pragma unroll
        for (int fm = 0; fm < FM; ++fm)
#pragma unroll
            for (int fn = 0; fn < FN; ++fn) {
                int row0 = i0 + wm * WR + fm * 16 + lg * 4;
                int col  = j0 + wn * WC + fn * 16 + lr;
                f16x4 q4;
#pragma unroll
                for (int rr = 0; rr < 4; ++rr) {
                    float vv = acc[fm][fn][rr] + (BIAS_I ? bias[row0 + rr] : bias[col]);
                    q4[rr] = (_Float16)vv;
                }
                size_t off;
                if constexpr (EPI == 1) {       // kfrag[mt][ks][ln][8]
                    int mt = col >> 5, mloc = col & 31;
                    int ks = row0 >> 4;
                    int ln2 = mloc + 32 * (lg >> 1);
                    off = (((size_t)mt * 16 + ks) * 64 + ln2) * 8 + (lg & 1) * 4;
                } else {                         // vfrag[mt][ms][dt][ln][8]
                    int mt = row0 >> 5, ms = (row0 >> 4) & 1;
                    int dt = col >> 5, dloc = col & 31;
                    int ln2 = dloc + 32 * (lg >> 1);
                    off = ((((size_t)mt * 2 + ms) * 8 + dt) * 64 + ln2) * 8 + (lg & 1) * 4;
                }
                *(f16x4*)((_Float16*)C + off) = q4;
            }
    }
}

// ---------------------------------------------------------------- flash attention
// 32x32 swapped-QK, pipelined, max-free softmax (p = exp2(s-16) exact).
// K/V staged from fragment-tiled global buffers (contiguous 1KB chunks) ->
// staging fully coalesced AND LDS fragment reads conflict-free (lane ln at ln*16).
__global__ __launch_bounds__(256, 2) void attn8_kernel(
    const _Float16* __restrict__ qb, const _Float16* __restrict__ kfrag,
    const _Float16* __restrict__ vfrag,
    _Float16* __restrict__ Opart, float* __restrict__ lpart,
    int nsp, int mspan)
{
    int id = blockIdx.x;
    int b = id & 7;                       // batch -> XCD affinity
    int rest = id >> 3;
    int qblk = rest & 15, sp = rest >> 4;
    int T = mspan >> 5;                   // tiles of 32 m

    __shared__ __align__(16) char lds[66560];   // 2 x (16K K | 16K V); epilogue reuse

    int t = threadIdx.x, ln = t & 63, w = t >> 6;
    int col = ln & 31, hi = ln >> 5;

    // fragment-tiled sources: 16KB per 32-m tile each (16 chunks x 1KB)
    const _Float16* kg = kfrag + (size_t)b * 524288 + (size_t)(sp * T) * 8192 + ln * 8;
    const _Float16* vg = vfrag + (size_t)b * 524288 + (size_t)(sp * T) * 8192 + ln * 8;
    int c0 = w * 4;                       // this wave's chunk base (4 chunks K + 4 V)
    int frd = ln * 16;                    // conflict-free LDS read offset (bytes)

    // Q fragments (pre-scaled by log2(e)/16 at fold time)
    f16x8 qf[16];
    {
        const _Float16* qp = qb + ((size_t)b * 2048 + qblk * 128 + w * 32 + col) * 256 + hi * 8;
#pragma unroll
        for (int ks = 0; ks < 16; ++ks) qf[ks] = *(const f16x8*)(qp + ks * 16);
    }

    f32x16 oacc[8] = {};
    float l_run = 0.f;
    unsigned W[8];

    // ---- prologue: stage tiles 0 and 1, drain, compute QK(0)+softmax(0)
#pragma unroll
    for (int i = 0; i < 4; ++i) {
        int c = c0 + i;
        gload_lds16(kg + c * 512,        lds + c * 1024);
        gload_lds16(vg + c * 512,        lds + 16384 + c * 1024);
        gload_lds16(kg + 8192 + c * 512, lds + 32768 + c * 1024);
        gload_lds16(vg + 8192 + c * 512, lds + 49152 + c * 1024);
    }
    asm volatile("s_waitcnt vmcnt(0)" ::: "memory");
    __builtin_amdgcn_sched_barrier(0);
    __builtin_amdgcn_s_barrier();
    {
        f32x16 sn = {};
        __builtin_amdgcn_s_setprio(1);
#pragma unroll
        for (int ks = 0; ks < 16; ++ks) {
            f16x8 kf = *(const f16x8*)(lds + ks * 1024 + frd);
            sn = MFMA32(kf, qf[ks], sn);
        }
        __builtin_amdgcn_s_setprio(0);
        float pv_[16];
#pragma unroll
        for (int i = 0; i < 16; ++i) pv_[i] = fexp2(sn[i] - 16.f);
        float psum = ((pv_[0]+pv_[1]) + (pv_[2]+pv_[3])) + ((pv_[4]+pv_[5]) + (pv_[6]+pv_[7]))
                   + ((pv_[8]+pv_[9]) + (pv_[10]+pv_[11])) + ((pv_[12]+pv_[13]) + (pv_[14]+pv_[15]));
        psum += __shfl_xor(psum, 32, 64);
        l_run = psum;
        W[0] = pkh(pv_[0],  pv_[1]);  W[1] = pkh(pv_[2],  pv_[3]);
        W[2] = pkh(pv_[4],  pv_[5]);  W[3] = pkh(pv_[6],  pv_[7]);
        W[4] = pkh(pv_[8],  pv_[9]);  W[5] = pkh(pv_[10], pv_[11]);
        W[6] = pkh(pv_[12], pv_[13]); W[7] = pkh(pv_[14], pv_[15]);
    }
    __builtin_amdgcn_s_barrier();   // all waves finished QK(0) reads

    // ---- main loop: iter tt = 0..T-2: PV(tt) || QK(tt+1)
    for (int tt = 0; tt < T - 1; ++tt) {
        char* myb = lds + (tt & 1) * 32768;          // tile tt (K | V)
        char* nxb = lds + ((tt + 1) & 1) * 32768;    // tile tt+1
        if (tt + 2 < T) {                            // K(tt+2) -> myb K-region
            const _Float16* ks2 = kg + (size_t)(tt + 2) * 8192;
#pragma unroll
            for (int i = 0; i < 4; ++i)
                gload_lds16(ks2 + (c0 + i) * 512, myb + (c0 + i) * 1024);
        }
        union { unsigned u[4]; f16x8 v; } pf0, pf1;
        {
            unsigned sx0 = hi ? W[0] : W[2], sx1 = hi ? W[1] : W[3];
            unsigned r0 = __shfl_xor(sx0, 32, 64), r1 = __shfl_xor(sx1, 32, 64);
            pf0.u[0] = hi ? r0 : W[0]; pf0.u[1] = hi ? r1 : W[1];
            pf0.u[2] = hi ? W[2] : r0; pf0.u[3] = hi ? W[3] : r1;
        }
        {
            unsigned sx0 = hi ? W[4] : W[6], sx1 = hi ? W[5] : W[7];
            unsigned r0 = __shfl_xor(sx0, 32, 64), r1 = __shfl_xor(sx1, 32, 64);
            pf1.u[0] = hi ? r0 : W[4]; pf1.u[1] = hi ? r1 : W[5];
            pf1.u[2] = hi ? W[6] : r0; pf1.u[3] = hi ? W[7] : r1;
        }
        // interleaved QK(tt+1) + PV(tt)
        f32x16 sn = {};
        __builtin_amdgcn_s_setprio(1);
#pragma unroll
        for (int g = 0; g < 4; ++g) {
#pragma unroll
            for (int k2 = 0; k2 < 4; ++k2) {
                int ks = g * 4 + k2;
                f16x8 kf = *(const f16x8*)(nxb + ks * 1024 + frd);
                sn = MFMA32(kf, qf[ks], sn);
            }
#pragma unroll
            for (int k2 = 0; k2 < 4; ++k2) {
                int idx = g * 4 + k2;
                f16x8 vf = *(const f16x8*)(myb + 16384 + idx * 1024 + frd);
                oacc[idx & 7] = MFMA32(vf, (g < 2) ? pf0.v : pf1.v, oacc[idx & 7]);
            }
        }
        __builtin_amdgcn_s_setprio(0);
        // max-free softmax(tt+1) -> W
        {
            float pv_[16];
#pragma unroll
            for (int i = 0; i < 16; ++i) pv_[i] = fexp2(sn[i] - 16.f);
            float psum = ((pv_[0]+pv_[1]) + (pv_[2]+pv_[3])) + ((pv_[4]+pv_[5]) + (pv_[6]+pv_[7]))
                       + ((pv_[8]+pv_[9]) + (pv_[10]+pv_[11])) + ((pv_[12]+pv_[13]) + (pv_[14]+pv_[15]));
            psum += __shfl_xor(psum, 32, 64);
            l_run += psum;
            W[0] = pkh(pv_[0],  pv_[1]);  W[1] = pkh(pv_[2],  pv_[3]);
            W[2] = pkh(pv_[4],  pv_[5]);  W[3] = pkh(pv_[6],  pv_[7]);
            W[4] = pkh(pv_[8],  pv_[9]);  W[5] = pkh(pv_[10], pv_[11]);
            W[6] = pkh(pv_[12], pv_[13]); W[7] = pkh(pv_[14], pv_[15]);
        }
        __builtin_amdgcn_s_barrier();          // all waves done reading V(tt), K(tt+1)
        __builtin_amdgcn_sched_barrier(0);
        if (tt + 2 < T) {                      // V(tt+2) -> myb V-region
            const _Float16* vs2 = vg + (size_t)(tt + 2) * 8192;
#pragma unroll
            for (int i = 0; i < 4; ++i)
                gload_lds16(vs2 + (c0 + i) * 512, myb + 16384 + (c0 + i) * 1024);
        }
        asm volatile("s_waitcnt vmcnt(4)" ::: "memory");   // K(tt+2) landed; V(tt+2) in flight
        __builtin_amdgcn_sched_barrier(0);
        __builtin_amdgcn_s_barrier();
    }

    // ---- final PV(T-1)
    asm volatile("s_waitcnt vmcnt(0)" ::: "memory");
    __builtin_amdgcn_sched_barrier(0);
    __builtin_amdgcn_s_barrier();
    {
        char* myb = lds + ((T - 1) & 1) * 32768;
        union { unsigned u[4]; f16x8 v; } pf0, pf1;
        {
            unsigned sx0 = hi ? W[0] : W[2], sx1 = hi ? W[1] : W[3];
            unsigned r0 = __shfl_xor(sx0, 32, 64), r1 = __shfl_xor(sx1, 32, 64);
            pf0.u[0] = hi ? r0 : W[0]; pf0.u[1] = hi ? r1 : W[1];
            pf0.u[2] = hi ? W[2] : r0; pf0.u[3] = hi ? W[3] : r1;
        }
        {
            unsigned sx0 = hi ? W[4] : W[6], sx1 = hi ? W[5] : W[7];
            unsigned r0 = __shfl_xor(sx0, 32, 64), r1 = __shfl_xor(sx1, 32, 64);
            pf1.u[0] = hi ? r0 : W[4]; pf1.u[1] = hi ? r1 : W[5];
            pf1.u[2] = hi ? W[6] : r0; pf1.u[3] = hi ? W[7] : r1;
        }
        __builtin_amdgcn_s_setprio(1);
#pragma unroll
        for (int idx = 0; idx < 16; ++idx) {
            f16x8 vf = *(const f16x8*)(myb + 16384 + idx * 1024 + frd);
            oacc[idx & 7] = MFMA32(vf, (idx < 8) ? pf0.v : pf1.v, oacc[idx & 7]);
        }
        __builtin_amdgcn_s_setprio(0);
    }
    __builtin_amdgcn_s_barrier();   // all waves done with K/V LDS

    // ---- epilogue: normalize, transpose via per-wave LDS, coalesced write
    _Float16* tr = (_Float16*)(lds + w * 16640);   // [32 q][260 d-stride]
    float invl = 1.0f / l_run;
#pragma unroll
    for (int dt = 0; dt < 8; ++dt)
#pragma unroll
        for (int g = 0; g < 4; ++g) {
            f16x4 q4;
#pragma unroll
            for (int e = 0; e < 4; ++e) q4[e] = (_Float16)(oacc[dt][g * 4 + e] * invl);
            int d0 = dt * 32 + g * 8 + 4 * hi;
            *(f16x4*)(tr + col * 260 + d0) = q4;
        }
    size_t region = ((size_t)((sp * 8 + b) * 16 + qblk)) * 32768;
    int rrow = ln >> 1, h = ln & 1;
    const _Float16* srcr = tr + rrow * 260 + h * 128;
    _Float16* dstr = Opart + region + (size_t)(w * 32 + rrow) * 256 + h * 128;
#pragma unroll
    for (int i = 0; i < 16; ++i)
        *(f16x8*)(dstr + i * 8) = *(const f16x8*)(srcr + i * 8);

    if (hi == 0) {
        int qi = w * 32 + col;
        lpart[((sp * 8 + b) * 16 + qblk) * 128 + qi] = l_run;
    }
}

// ---------------------------------------------------------------- split combine
__global__ __launch_bounds__(256) void combine3_kernel(
    const _Float16* __restrict__ Opart, const float* __restrict__ lpart,
    _Float16* __restrict__ abuf, int nsp)
{
    int id = blockIdx.x;
    int b = id & 7, qb = (id >> 3) & 15, dh = id >> 7;
    int t = threadIdx.x;
    __shared__ float cf[4][128];
    if (t < 128) {
        float l[4], s = 0.f;
        for (int sp = 0; sp < nsp; ++sp) {
            l[sp] = lpart[((sp * 8 + b) * 16 + qb) * 128 + t];
            s += l[sp];
        }
        float inv = 1.0f / s;
        for (int sp = 0; sp < nsp; ++sp) cf[sp][t] = l[sp] * inv;
    }
    __syncthreads();
    size_t rb = ((size_t)(b * 16 + qb)) * 32768;
#pragma unroll
    for (int i = 0; i < 8; ++i) {
        int flat = i * 2048 + t * 8;
        int qi = flat >> 7, dl = flat & 127;
        float acc[8] = {};
        for (int sp = 0; sp < nsp; ++sp) {
            f16x8 v = *(const f16x8*)(Opart + (size_t)sp * 4194304 + rb +
                                      (size_t)qi * 256 + dh * 128 + dl);
            float c = cf[sp][qi];
#pragma unroll
            for (int e = 0; e < 8; ++e) acc[e] += c * (float)v[e];
        }
        f16x8 r;
#pragma unroll
        for (int e = 0; e < 8; ++e) r[e] = (_Float16)acc[e];
        *(f16x8*)(abuf + ((size_t)b * 2048 + qb * 128 + qi) * 256 + dh * 128 + dl) = r;
    }
}

// ---------------------------------------------------------------- launch
extern "C" void kernel_launch(void* const* d_in, const int* in_sizes, int n_in,
                              void* d_out, int out_size, void* d_ws, size_t ws_size,
                              hipStream_t stream) {
    const float* x     = (const float*)d_in[0];
    const float* gamma = (const float*)d_in[1];
    const float* beta  = (const float*)d_in[2];
    const float* Wq    = (const float*)d_in[3];
    const float* bq    = (const float*)d_in[4];
    const float* Wk    = (const float*)d_in[5];
    const float* bk    = (const float*)d_in[6];
    const float* Wv    = (const float*)d_in[7];
    const float* bv    = (const float*)d_in[8];
    const float* Wp    = (const float*)d_in[9];
    const float* bp    = (const float*)d_in[10];
    float* out = (float*)d_out;

    char* ws = (char*)d_ws;
    float* sums  = (float*)ws;                     // 512 f32 (zeroed each launch)
    float* bfold = (float*)(ws + 2048);            // 768 f32
    float* lpart = (float*)(ws + 8192);            // up to 256KB
    _Float16* wbf   = (_Float16*)(ws + 524288);    // 512KB: Wq'|Wk'|Wv'|Wp f16
    _Float16* xt    = (_Float16*)(ws + 1048576);   // 8MB [8][2048][256]
    _Float16* qbuf  = (_Float16*)(ws + 9437184);   // 8MB [8][2048][256]
    _Float16* kfrag = (_Float16*)(ws + 17825792);  // 8MB [8][64mt][16ks][64][8]
    _Float16* vfrag = (_Float16*)(ws + 26214400);  // 8MB [8][64mt][2ms][8dt][64][8]
    _Float16* Opart = (_Float16*)(ws + 34603008);  // nsp*8MB
    _Float16* abuf  = xt;                          // xt dead after v-gemm

    int nsp = (ws_size >= (size_t)34603008 + 4ull * 8388608ull) ? 4 : 2;
    int mspan = 2048 / nsp;

    const long SB = 524288;

    hipMemsetAsync(sums, 0, 2048, stream);
    trans_stats_kernel<<<dim3(32, 4, 8), 256, 0, stream>>>(x, xt, sums);
    fold_kernel<<<448, 256, 0, stream>>>(Wq, Wk, Wv, Wp, bq, bk, bv,
                                         gamma, beta, sums, wbf, bfold);
    // q: [b][n][256] = xt . Wq'^T + bq'
    gemm_nt<64, 4, 1, _Float16, false, false, 0><<<dim3(4, 16, 8), 256, 0, stream>>>(
        xt, SB, wbf, 0, bfold, nullptr, 0, qbuf, SB, 256);
    // kfrag: fragment-tiled K (rows = k-channel, cols = m)
    gemm_nt<64, 4, 1, _Float16, true, false, 1><<<dim3(32, 2, 8), 256, 0, stream>>>(
        wbf + 65536, 0, xt, SB, bfold + 256, nullptr, 0, kfrag, SB, 2048);
    // vfrag: fragment-tiled V (rows = m, cols = d)
    gemm_nt<64, 4, 1, _Float16, false, false, 2><<<dim3(4, 16, 8), 256, 0, stream>>>(
        xt, SB, wbf + 131072, 0, bfold + 512, nullptr, 0, vfrag, SB, 256);
    attn8_kernel<<<128 * nsp, 256, 0, stream>>>(qbuf, kfrag, vfrag, Opart, lpart,
                                                nsp, mspan);
    combine3_kernel<<<256, 256, 0, stream>>>(Opart, lpart, abuf, nsp);
    // out: [b][o][n] = Wp . attn^T + bp + x
    gemm_nt<64, 4, 1, float, true, true, 0><<<dim3(32, 2, 8), 256, 0, stream>>>(
        wbf + 196608, 0, abuf, SB, bp, x, SB, out, SB, 2048);
}

// Round 13
// 108.220 us; speedup vs baseline: 1.0397x; 1.0397x over previous
//
#include <hip/hip_runtime.h>
#include <hip/hip_fp16.h>

typedef _Float16 f16x8 __attribute__((ext_vector_type(8)));
typedef _Float16 f16x4 __attribute__((ext_vector_type(4)));
typedef float f32x4 __attribute__((ext_vector_type(4)));
typedef float f32x16 __attribute__((ext_vector_type(16)));

#define MFMA16(a, b, c) __builtin_amdgcn_mfma_f32_16x16x32_f16(a, b, c, 0, 0, 0)
#define MFMA32(a, b, c) __builtin_amdgcn_mfma_f32_32x32x16_f16(a, b, c, 0, 0, 0)

__device__ __forceinline__ void gload_lds16(const _Float16* g, void* l) {
    __builtin_amdgcn_global_load_lds(
        (const __attribute__((address_space(1))) void*)g,
        (__attribute__((address_space(3))) void*)l, 16, 0, 0);
}

__device__ __forceinline__ unsigned pkh(float a, float b) {
    typedef __fp16 fp16v2 __attribute__((ext_vector_type(2)));
    fp16v2 h = __builtin_amdgcn_cvt_pkrtz(a, b);
    return __builtin_bit_cast(unsigned, h);
}

__device__ __forceinline__ float fexp2(float x) {
#if __has_builtin(__builtin_amdgcn_exp2f)
    return __builtin_amdgcn_exp2f(x);
#else
    return exp2f(x);
#endif
}

// -------------------------------------------- transpose x -> f16 [b][n][c] + BN stats
__global__ __launch_bounds__(256) void trans_stats_kernel(
    const float* __restrict__ x, _Float16* __restrict__ xt,
    float* __restrict__ sums)
{
    __shared__ float tile[64][65];
    int t = threadIdx.x;
    int b = blockIdx.z, c0 = blockIdx.y * 64, n0 = blockIdx.x * 64;
    int nl = t & 63, cq = t >> 6;
#pragma unroll
    for (int r = 0; r < 16; ++r) {
        int cl = cq * 16 + r;
        tile[cl][nl] = x[((size_t)b * 256 + c0 + cl) * 2048 + n0 + nl];
    }
    __syncthreads();
    int cl2 = t & 63, nq = t >> 6;
#pragma unroll
    for (int r = 0; r < 16; ++r) {
        int nl2 = nq * 16 + r;
        xt[((size_t)b * 2048 + n0 + nl2) * 256 + c0 + cl2] = (_Float16)tile[cl2][nl2];
    }
    if (t < 64) {
        float s = 0.f, ss = 0.f;
#pragma unroll
        for (int j = 0; j < 64; ++j) {
            float v = tile[t][j];
            s += v; ss += v * v;
        }
        atomicAdd(&sums[c0 + t], s);
        atomicAdd(&sums[256 + c0 + t], ss);
    }
}

// ---------------------------------------------------------------- fold BN into weights
// wbf layout: [Wq' | Wv' | Wk' | Wp]  (q,v adjacent so the fused qv-GEMM's B is contiguous)
__global__ __launch_bounds__(256) void fold_kernel(
    const float* __restrict__ Wq, const float* __restrict__ Wk,
    const float* __restrict__ Wv, const float* __restrict__ Wp,
    const float* __restrict__ bq, const float* __restrict__ bk,
    const float* __restrict__ bv,
    const float* __restrict__ gamma, const float* __restrict__ beta,
    const float* __restrict__ sums,
    _Float16* __restrict__ wbf, float* __restrict__ bfold)
{
    int t = threadIdx.x, bid = blockIdx.x;
    if (bid >= 192) {                       // cast Wp
        int i = (bid - 192) * 256 + t;
        wbf[3 * 65536 + i] = (_Float16)Wp[i];
        return;
    }
    __shared__ float sc[256], sh[256];
    if (t < 256) {
        float mean = sums[t] * (1.f / 16384.f);
        float var  = sums[256 + t] * (1.f / 16384.f) - mean * mean;
        float rstd = rsqrtf(var + 1e-5f);
        float s = rstd * gamma[t];
        sc[t] = s;
        sh[t] = beta[t] - mean * s;
    }
    __syncthreads();
    const float QS = 0.09016844005556021f;  // log2(e)/16
    int mat = bid >> 6;                     // 0=q 1=k 2=v
    int o = (bid & 63) * 4 + (t >> 6);
    int lane = t & 63;
    const float* W  = (mat == 0) ? Wq : (mat == 1) ? Wk : Wv;
    const float* bb = (mat == 0) ? bq : (mat == 1) ? bk : bv;
    float qs = (mat == 0) ? QS : 1.f;
    int wslot = (mat == 0) ? 0 : (mat == 1) ? 131072 : 65536;   // q | v | k
    float dot = 0.f;
    _Float16* wd = wbf + wslot + o * 256;
#pragma unroll
    for (int i = 0; i < 4; ++i) {
        int c = lane * 4 + i;
        float wv_ = W[o * 256 + c];
        dot += wv_ * sh[c];
        wd[c] = (_Float16)(wv_ * sc[c] * qs);
    }
#pragma unroll
    for (int off = 32; off > 0; off >>= 1) dot += __shfl_down(dot, off, 64);
    if (lane == 0) bfold[mat * 256 + o] = qs * (bb[o] + dot);
}

// ---------------------------------------------------------------- NT GEMM (m97-style)
// EPI: 0 = row-major C; 1 = K-fragment layout; 2 = V-fragment layout;
//      3 = fused qv: j0<256 -> row-major q into C, else V-fragment into Caux.
template<int BN, int WGM, int WGN, typename OT, bool BIAS_I, bool RES, int EPI>
__global__ __launch_bounds__(256, 3) void gemm_nt(
    const _Float16* __restrict__ Aall, long strideA,
    const _Float16* __restrict__ Ball, long strideB,
    const float* __restrict__ bias,
    const float* __restrict__ resid, long strideR,
    OT* __restrict__ Call, long strideC, int Nn,
    OT* __restrict__ Cauxall)
{
    constexpr int BM = 128;
    constexpr int WR = BM / WGM;
    constexpr int WC = BN / WGN;
    constexpr int FM = WR / 16, FN = WC / 16;
    constexpr int BUFSZ = 8192 + BN * 64;
    constexpr int NI = 8 + BN / 16;
    constexpr int PW = NI / 4;

    int b = blockIdx.z;
    const _Float16* A  = Aall + (size_t)b * strideA;
    const _Float16* Bm = Ball + (size_t)b * strideB;
    OT* C = Call + (size_t)b * strideC;
    int i0 = blockIdx.y * BM, j0 = blockIdx.x * BN;

    __shared__ __align__(16) char lds[2 * BUFSZ];

    int t = threadIdx.x, lane = t & 63, w = t >> 6;
    int lr = lane & 15, lg = lane >> 4;
    int wm = w % WGM, wn = w / WGM;

    int soff = (lane >> 2) * 256 + (((lane & 3) ^ ((lane >> 3) & 3))) * 8;
    int lgx16 = ((lg ^ ((lr >> 1) & 3))) * 16;

    f32x4 acc[FM][FN] = {};

    auto stage = [&](int kk, int buf) {
#pragma unroll
        for (int i = 0; i < PW; ++i) {
            int u = w * PW + i;
            if (u < 8)
                gload_lds16(A + (size_t)(i0 + u * 16) * 256 + kk * 32 + soff,
                            lds + buf * BUFSZ + u * 1024);
            else
                gload_lds16(Bm + (size_t)(j0 + (u - 8) * 16) * 256 + kk * 32 + soff,
                            lds + buf * BUFSZ + 8192 + (u - 8) * 1024);
        }
    };

    stage(0, 0);
    __syncthreads();
    int buf = 0;
#pragma unroll
    for (int kk = 0; kk < 8; ++kk) {
        if (kk + 1 < 8) stage(kk + 1, buf ^ 1);
        const char* ab = lds + buf * BUFSZ;
        const char* bb = ab + 8192;
        f16x8 af[FM], bf[FN];
#pragma unroll
        for (int f = 0; f < FM; ++f)
            af[f] = *(const f16x8*)(ab + (wm * WR + f * 16 + lr) * 64 + lgx16);
#pragma unroll
        for (int f = 0; f < FN; ++f)
            bf[f] = *(const f16x8*)(bb + (wn * WC + f * 16 + lr) * 64 + lgx16);
        __builtin_amdgcn_s_setprio(1);
#pragma unroll
        for (int fm = 0; fm < FM; ++fm)
#pragma unroll
            for (int fn = 0; fn < FN; ++fn)
                acc[fm][fn] = MFMA16(af[fm], bf[fn], acc[fm][fn]);
        __builtin_amdgcn_s_setprio(0);
        __syncthreads();
        buf ^= 1;
    }
    if constexpr (EPI == 0) {
#pragma unroll
        for (int fm = 0; fm < FM; ++fm)
#pragma unroll
            for (int fn = 0; fn < FN; ++fn)
#pragma unroll
                for (int rr = 0; rr < 4; ++rr) {
                    int row = i0 + wm * WR + fm * 16 + lg * 4 + rr;
                    int col = j0 + wn * WC + fn * 16 + lr;
                    float vv = acc[fm][fn][rr] + (BIAS_I ? bias[row] : bias[col]);
                    if (RES) vv += resid[(size_t)b * strideR + (size_t)row * Nn + col];
                    C[(size_t)row * Nn + col] = (OT)vv;
                }
    } else if constexpr (EPI == 1) {
#pragma unroll
        for (int fm = 0; fm < FM; ++fm)
#pragma unroll
            for (int fn = 0; fn < FN; ++fn) {
                int row0 = i0 + wm * WR + fm * 16 + lg * 4;
                int col  = j0 + wn * WC + fn * 16 + lr;
                f16x4 q4;
#pragma unroll
                for (int rr = 0; rr < 4; ++rr)
                    q4[rr] = (_Float16)(acc[fm][fn][rr] + bias[row0 + rr]);
                int mt = col >> 5, mloc = col & 31;
                int ks = row0 >> 4;
                int ln2 = mloc + 32 * (lg >> 1);
                size_t off = (((size_t)mt * 16 + ks) * 64 + ln2) * 8 + (lg & 1) * 4;
                *(f16x4*)((_Float16*)C + off) = q4;
            }
    } else {   // EPI 2 or 3
        bool vreg = (EPI == 2) || (j0 >= 256);
#pragma unroll
        for (int fm = 0; fm < FM; ++fm)
#pragma unroll
            for (int fn = 0; fn < FN; ++fn) {
                int row0 = i0 + wm * WR + fm * 16 + lg * 4;
                int col  = j0 + wn * WC + fn * 16 + lr;
                if (vreg) {
                    int colv = (EPI == 3) ? col - 256 : col;
                    const float bv_ = (EPI == 3) ? bias[256 + col] : bias[colv];
                    f16x4 q4;
#pragma unroll
                    for (int rr = 0; rr < 4; ++rr)
                        q4[rr] = (_Float16)(acc[fm][fn][rr] + bv_);
                    int mt = row0 >> 5, ms = (row0 >> 4) & 1;
                    int dt = colv >> 5, dloc = colv & 31;
                    int ln2 = dloc + 32 * (lg >> 1);
                    size_t off = ((((size_t)mt * 2 + ms) * 8 + dt) * 64 + ln2) * 8 + (lg & 1) * 4;
                    OT* dst = (EPI == 3) ? (Cauxall + (size_t)b * strideC) : C;
                    *(f16x4*)((_Float16*)dst + off) = q4;
                } else {   // EPI3 q region: row-major into C
#pragma unroll
                    for (int rr = 0; rr < 4; ++rr) {
                        float vv = acc[fm][fn][rr] + bias[col];
                        C[(size_t)(row0 + rr) * 256 + col] = (OT)vv;
                    }
                }
            }
    }
}

// ---------------------------------------------------------------- flash attention
// 32x32 swapped-QK, max-free softmax (p = exp2(s-16)), fragment-tiled K/V staging
// (conflict-free LDS), SINGLE barrier per tile: K double-buffer + V TRIPLE-buffer
// (80KB LDS). K(t+2),V(t+2) issued together at iter top; counted vmcnt(4) keeps
// V(t+2) in flight across the barrier.
__global__ __launch_bounds__(256, 2) void attn9_kernel(
    const _Float16* __restrict__ qb, const _Float16* __restrict__ kfrag,
    const _Float16* __restrict__ vfrag,
    _Float16* __restrict__ Opart, float* __restrict__ lpart,
    int nsp, int mspan)
{
    int id = blockIdx.x;
    int b = id & 7;                       // batch -> XCD affinity
    int rest = id >> 3;
    int qblk = rest & 15, sp = rest >> 4;
    int T = mspan >> 5;                   // tiles of 32 m

    __shared__ __align__(16) char lds[81920];   // K[2] @0,16K ; V[3] @32K,48K,64K

    int t = threadIdx.x, ln = t & 63, w = t >> 6;
    int col = ln & 31, hi = ln >> 5;

    const _Float16* kg = kfrag + (size_t)b * 524288 + (size_t)(sp * T) * 8192 + ln * 8;
    const _Float16* vg = vfrag + (size_t)b * 524288 + (size_t)(sp * T) * 8192 + ln * 8;
    int c0 = w * 4;                       // this wave's 4 chunks
    int frd = ln * 16;                    // conflict-free LDS read offset

    f16x8 qf[16];
    {
        const _Float16* qp = qb + ((size_t)b * 2048 + qblk * 128 + w * 32 + col) * 256 + hi * 8;
#pragma unroll
        for (int ks = 0; ks < 16; ++ks) qf[ks] = *(const f16x8*)(qp + ks * 16);
    }

    f32x16 oacc[8] = {};
    float l_run = 0.f;
    unsigned W[8];

    // ---- prologue: K(0),K(1),V(0),V(1); drain; QK(0)+softmax(0)
#pragma unroll
    for (int i = 0; i < 4; ++i) {
        int c = c0 + i;
        gload_lds16(kg + c * 512,        lds + c * 1024);            // K(0)->K[0]
        gload_lds16(kg + 8192 + c * 512, lds + 16384 + c * 1024);    // K(1)->K[1]
        gload_lds16(vg + c * 512,        lds + 32768 + c * 1024);    // V(0)->V[0]
        gload_lds16(vg + 8192 + c * 512, lds + 49152 + c * 1024);    // V(1)->V[1]
    }
    asm volatile("s_waitcnt vmcnt(0)" ::: "memory");
    __builtin_amdgcn_sched_barrier(0);
    __builtin_amdgcn_s_barrier();
    {
        f32x16 sn = {};
        __builtin_amdgcn_s_setprio(1);
#pragma unroll
        for (int ks = 0; ks < 16; ++ks) {
            f16x8 kf = *(const f16x8*)(lds + ks * 1024 + frd);
            sn = MFMA32(kf, qf[ks], sn);
        }
        __builtin_amdgcn_s_setprio(0);
        float pv_[16];
#pragma unroll
        for (int i = 0; i < 16; ++i) pv_[i] = fexp2(sn[i] - 16.f);
        float psum = ((pv_[0]+pv_[1]) + (pv_[2]+pv_[3])) + ((pv_[4]+pv_[5]) + (pv_[6]+pv_[7]))
                   + ((pv_[8]+pv_[9]) + (pv_[10]+pv_[11])) + ((pv_[12]+pv_[13]) + (pv_[14]+pv_[15]));
        psum += __shfl_xor(psum, 32, 64);
        l_run = psum;
        W[0] = pkh(pv_[0],  pv_[1]);  W[1] = pkh(pv_[2],  pv_[3]);
        W[2] = pkh(pv_[4],  pv_[5]);  W[3] = pkh(pv_[6],  pv_[7]);
        W[4] = pkh(pv_[8],  pv_[9]);  W[5] = pkh(pv_[10], pv_[11]);
        W[6] = pkh(pv_[12], pv_[13]); W[7] = pkh(pv_[14], pv_[15]);
    }
    __builtin_amdgcn_s_barrier();   // all waves done reading K(0)

    // ---- main loop: iter tt: PV(tt) || QK(tt+1); one barrier per iter
    for (int tt = 0; tt < T - 1; ++tt) {
        const char* kb = lds + ((tt + 1) & 1) * 16384;        // K(tt+1)
        const char* vb = lds + 32768 + (tt % 3) * 16384;      // V(tt)
        if (tt + 2 < T) {                                     // stage K,V (tt+2)
            const _Float16* sK = kg + (size_t)(tt + 2) * 8192;
            const _Float16* sV = vg + (size_t)(tt + 2) * 8192;
            char* kd = lds + (tt & 1) * 16384;
            char* vd = lds + 32768 + ((tt + 2) % 3) * 16384;
#pragma unroll
            for (int i = 0; i < 4; ++i) {
                gload_lds16(sK + (c0 + i) * 512, kd + (c0 + i) * 1024);
                gload_lds16(sV + (c0 + i) * 512, vd + (c0 + i) * 1024);
            }
        }
        union { unsigned u[4]; f16x8 v; } pf0, pf1;
        {
            unsigned sx0 = hi ? W[0] : W[2], sx1 = hi ? W[1] : W[3];
            unsigned r0 = __shfl_xor(sx0, 32, 64), r1 = __shfl_xor(sx1, 32, 64);
            pf0.u[0] = hi ? r0 : W[0]; pf0.u[1] = hi ? r1 : W[1];
            pf0.u[2] = hi ? W[2] : r0; pf0.u[3] = hi ? W[3] : r1;
        }
        {
            unsigned sx0 = hi ? W[4] : W[6], sx1 = hi ? W[5] : W[7];
            unsigned r0 = __shfl_xor(sx0, 32, 64), r1 = __shfl_xor(sx1, 32, 64);
            pf1.u[0] = hi ? r0 : W[4]; pf1.u[1] = hi ? r1 : W[5];
            pf1.u[2] = hi ? W[6] : r0; pf1.u[3] = hi ? W[7] : r1;
        }
        // interleaved QK(tt+1) + PV(tt)
        f32x16 sn = {};
        __builtin_amdgcn_s_setprio(1);
#pragma unroll
        for (int g = 0; g < 4; ++g) {
#pragma unroll
            for (int k2 = 0; k2 < 4; ++k2) {
                int ks = g * 4 + k2;
                f16x8 kf = *(const f16x8*)(kb + ks * 1024 + frd);
                sn = MFMA32(kf, qf[ks], sn);
            }
#pragma unroll
            for (int k2 = 0; k2 < 4; ++k2) {
                int idx = g * 4 + k2;
                f16x8 vf = *(const f16x8*)(vb + 16384 * 0 + idx * 1024 + frd);
                oacc[idx & 7] = MFMA32(vf, (g < 2) ? pf0.v : pf1.v, oacc[idx & 7]);
            }
        }
        __builtin_amdgcn_s_setprio(0);
        // max-free softmax(tt+1) -> W
        {
            float pv_[16];
#pragma unroll
            for (int i = 0; i < 16; ++i) pv_[i] = fexp2(sn[i] - 16.f);
            float psum = ((pv_[0]+pv_[1]) + (pv_[2]+pv_[3])) + ((pv_[4]+pv_[5]) + (pv_[6]+pv_[7]))
                       + ((pv_[8]+pv_[9]) + (pv_[10]+pv_[11])) + ((pv_[12]+pv_[13]) + (pv_[14]+pv_[15]));
            psum += __shfl_xor(psum, 32, 64);
            l_run += psum;
            W[0] = pkh(pv_[0],  pv_[1]);  W[1] = pkh(pv_[2],  pv_[3]);
            W[2] = pkh(pv_[4],  pv_[5]);  W[3] = pkh(pv_[6],  pv_[7]);
            W[4] = pkh(pv_[8],  pv_[9]);  W[5] = pkh(pv_[10], pv_[11]);
            W[6] = pkh(pv_[12], pv_[13]); W[7] = pkh(pv_[14], pv_[15]);
        }
        // single sync point: drain own K(tt+2) (V(tt+2) stays in flight), publish
        asm volatile("s_waitcnt vmcnt(4)" ::: "memory");
        __builtin_amdgcn_sched_barrier(0);
        __builtin_amdgcn_s_barrier();
    }

    // ---- final PV(T-1)
    asm volatile("s_waitcnt vmcnt(0)" ::: "memory");
    __builtin_amdgcn_sched_barrier(0);
    __builtin_amdgcn_s_barrier();
    {
        const char* vb = lds + 32768 + ((T - 1) % 3) * 16384;
        union { unsigned u[4]; f16x8 v; } pf0, pf1;
        {
            unsigned sx0 = hi ? W[0] : W[2], sx1 = hi ? W[1] : W[3];
            unsigned r0 = __shfl_xor(sx0, 32, 64), r1 = __shfl_xor(sx1, 32, 64);
            pf0.u[0] = hi ? r0 : W[0]; pf0.u[1] = hi ? r1 : W[1];
            pf0.u[2] = hi ? W[2] : r0; pf0.u[3] = hi ? W[3] : r1;
        }
        {
            unsigned sx0 = hi ? W[4] : W[6], sx1 = hi ? W[5] : W[7];
            unsigned r0 = __shfl_xor(sx0, 32, 64), r1 = __shfl_xor(sx1, 32, 64);
            pf1.u[0] = hi ? r0 : W[4]; pf1.u[1] = hi ? r1 : W[5];
            pf1.u[2] = hi ? W[6] : r0; pf1.u[3] = hi ? W[7] : r1;
        }
        __builtin_amdgcn_s_setprio(1);
#pragma unroll
        for (int idx = 0; idx < 16; ++idx) {
            f16x8 vf = *(const f16x8*)(vb + idx * 1024 + frd);
            oacc[idx & 7] = MFMA32(vf, (idx < 8) ? pf0.v : pf1.v, oacc[idx & 7]);
        }
        __builtin_amdgcn_s_setprio(0);
    }
    __builtin_amdgcn_s_barrier();   // all waves done with K/V LDS

    // ---- epilogue: normalize, transpose via per-wave LDS, coalesced write
    _Float16* tr = (_Float16*)(lds + w * 16640);   // [32 q][260 d-stride]
    float invl = 1.0f / l_run;
#pragma unroll
    for (int dt = 0; dt < 8; ++dt)
#pragma unroll
        for (int g = 0; g < 4; ++g) {
            f16x4 q4;
#pragma unroll
            for (int e = 0; e < 4; ++e) q4[e] = (_Float16)(oacc[dt][g * 4 + e] * invl);
            int d0 = dt * 32 + g * 8 + 4 * hi;
            *(f16x4*)(tr + col * 260 + d0) = q4;
        }
    size_t region = ((size_t)((sp * 8 + b) * 16 + qblk)) * 32768;
    int rrow = ln >> 1, h = ln & 1;
    const _Float16* srcr = tr + rrow * 260 + h * 128;
    _Float16* dstr = Opart + region + (size_t)(w * 32 + rrow) * 256 + h * 128;
#pragma unroll
    for (int i = 0; i < 16; ++i)
        *(f16x8*)(dstr + i * 8) = *(const f16x8*)(srcr + i * 8);

    if (hi == 0) {
        int qi = w * 32 + col;
        lpart[((sp * 8 + b) * 16 + qblk) * 128 + qi] = l_run;
    }
}

// ---------------------------------------------------------------- split combine
__global__ __launch_bounds__(256) void combine3_kernel(
    const _Float16* __restrict__ Opart, const float* __restrict__ lpart,
    _Float16* __restrict__ abuf, int nsp)
{
    int id = blockIdx.x;
    int b = id & 7, qb = (id >> 3) & 15, dh = id >> 7;
    int t = threadIdx.x;
    __shared__ float cf[4][128];
    if (t < 128) {
        float l[4], s = 0.f;
        for (int sp = 0; sp < nsp; ++sp) {
            l[sp] = lpart[((sp * 8 + b) * 16 + qb) * 128 + t];
            s += l[sp];
        }
        float inv = 1.0f / s;
        for (int sp = 0; sp < nsp; ++sp) cf[sp][t] = l[sp] * inv;
    }
    __syncthreads();
    size_t rb = ((size_t)(b * 16 + qb)) * 32768;
#pragma unroll
    for (int i = 0; i < 8; ++i) {
        int flat = i * 2048 + t * 8;
        int qi = flat >> 7, dl = flat & 127;
        float acc[8] = {};
        for (int sp = 0; sp < nsp; ++sp) {
            f16x8 v = *(const f16x8*)(Opart + (size_t)sp * 4194304 + rb +
                                      (size_t)qi * 256 + dh * 128 + dl);
            float c = cf[sp][qi];
#pragma unroll
            for (int e = 0; e < 8; ++e) acc[e] += c * (float)v[e];
        }
        f16x8 r;
#pragma unroll
        for (int e = 0; e < 8; ++e) r[e] = (_Float16)acc[e];
        *(f16x8*)(abuf + ((size_t)b * 2048 + qb * 128 + qi) * 256 + dh * 128 + dl) = r;
    }
}

// ---------------------------------------------------------------- launch
extern "C" void kernel_launch(void* const* d_in, const int* in_sizes, int n_in,
                              void* d_out, int out_size, void* d_ws, size_t ws_size,
                              hipStream_t stream) {
    const float* x     = (const float*)d_in[0];
    const float* gamma = (const float*)d_in[1];
    const float* beta  = (const float*)d_in[2];
    const float* Wq    = (const float*)d_in[3];
    const float* bq    = (const float*)d_in[4];
    const float* Wk    = (const float*)d_in[5];
    const float* bk    = (const float*)d_in[6];
    const float* Wv    = (const float*)d_in[7];
    const float* bv    = (const float*)d_in[8];
    const float* Wp    = (const float*)d_in[9];
    const float* bp    = (const float*)d_in[10];
    float* out = (float*)d_out;

    char* ws = (char*)d_ws;
    float* sums  = (float*)ws;                     // 512 f32 (zeroed each launch)
    float* bfold = (float*)(ws + 2048);            // 768 f32
    float* lpart = (float*)(ws + 8192);            // up to 256KB
    _Float16* wbf   = (_Float16*)(ws + 524288);    // 512KB: Wq'|Wv'|Wk'|Wp f16
    _Float16* xt    = (_Float16*)(ws + 1048576);   // 8MB [8][2048][256]
    _Float16* qbuf  = (_Float16*)(ws + 9437184);   // 8MB [8][2048][256]
    _Float16* kfrag = (_Float16*)(ws + 17825792);  // 8MB [8][64mt][16ks][64][8]
    _Float16* vfrag = (_Float16*)(ws + 26214400);  // 8MB [8][64mt][2ms][8dt][64][8]
    _Float16* Opart = (_Float16*)(ws + 34603008);  // nsp*8MB
    _Float16* abuf  = xt;                          // xt dead after qv-gemm

    int nsp = (ws_size >= (size_t)34603008 + 4ull * 8388608ull) ? 4 : 2;
    int mspan = 2048 / nsp;

    const long SB = 524288;

    hipMemsetAsync(sums, 0, 2048, stream);
    trans_stats_kernel<<<dim3(32, 4, 8), 256, 0, stream>>>(x, xt, sums);
    fold_kernel<<<448, 256, 0, stream>>>(Wq, Wk, Wv, Wp, bq, bk, bv,
                                         gamma, beta, sums, wbf, bfold);
    // fused q+v: B = [Wq'|Wv'] (512 rows); j0<256 -> qbuf row-major, else vfrag
    gemm_nt<128, 2, 2, _Float16, false, false, 3><<<dim3(4, 16, 8), 256, 0, stream>>>(
        xt, SB, wbf, 0, bfold, nullptr, 0, qbuf, SB, 256, vfrag);
    // kfrag: fragment-tiled K (rows = k-channel, cols = m)
    gemm_nt<64, 4, 1, _Float16, true, false, 1><<<dim3(32, 2, 8), 256, 0, stream>>>(
        wbf + 131072, 0, xt, SB, bfold + 256, nullptr, 0, kfrag, SB, 2048, (_Float16*)nullptr);
    attn9_kernel<<<128 * nsp, 256, 0, stream>>>(qbuf, kfrag, vfrag, Opart, lpart,
                                                nsp, mspan);
    combine3_kernel<<<256, 256, 0, stream>>>(Opart, lpart, abuf, nsp);
    // out: [b][o][n] = Wp . attn^T + bp + x
    gemm_nt<64, 4, 1, float, true, true, 0><<<dim3(32, 2, 8), 256, 0, stream>>>(
        wbf + 196608, 0, abuf, SB, bp, x, SB, out, SB, 2048, (float*)nullptr);
}